// Round 2
// baseline (489.766 us; speedup 1.0000x reference)
//
#include <hip/hip_runtime.h>

#define MBLK 32

typedef __attribute__((ext_vector_type(8))) short bf16x8;
typedef __attribute__((ext_vector_type(4))) short bf16x4;
typedef __attribute__((ext_vector_type(4))) float f32x4;

__device__ __forceinline__ unsigned short f2bf(float x){
  unsigned int u = __float_as_uint(x);
  u = u + 0x7FFFu + ((u >> 16) & 1u);
  return (unsigned short)(u >> 16);
}
__device__ __forceinline__ float bf2f(unsigned short s){
  return __uint_as_float(((unsigned int)s) << 16);
}
__device__ __forceinline__ float sigm(float x){
  return __builtin_amdgcn_rcpf(1.0f + __expf(-x));
}
__device__ __forceinline__ float tanh_(float x){
  return 1.0f - 2.0f*__builtin_amdgcn_rcpf(__expf(2.0f*x) + 1.0f);
}

// 1024-thread block, 16 waves, MBLK=32, 256 blocks = 1 block/CU.
// __launch_bounds__(1024,4) -> <=128 VGPR -> 4 waves/SIMD (2x the 268us
// baseline) WITHOUT weight duplication: weight B-frags are Bf[2][6] = 48
// VGPR/thread (the 196KB weight matrix spread over 1024 threads).
// Gate split: wave wv owns hidden units wv*8..wv*8+7, all 4 gates, as 2
// N-tiles. Tile n2, lane i -> gate n2*2+(i&1), hidden wv*8+(i>>1).
// Lanes i / i^1 hold complementary gate pairs for the same hidden unit:
// 8 shfl_xor(.,1) per step exchange them (each lane sends acc[par^1],
// receives its missing f/o or i/g gates). Lane parity par=i&1 picks which
// 16-sample half (mt) the lane finishes in the nonlinearity.
// Double-buffered [x(64)|h(128)] bf16 tile, row stride 200 shorts
// (100 dwords = 4 mod 32 -> balanced banks for ds_read_b128 frags).
__global__ __launch_bounds__(1024, 4) void traj_kernel(
    const float* __restrict__ img, const float* __restrict__ obs_pos,
    const int* __restrict__ hist, const float* __restrict__ rel,
    const float* __restrict__ h0, const float* __restrict__ W_ih,
    const float* __restrict__ W_hh, const float* __restrict__ b_ih,
    const float* __restrict__ b_hh, const float* __restrict__ eW,
    const float* __restrict__ eb, const float* __restrict__ pW,
    const float* __restrict__ pb, float* __restrict__ out)
{
  __shared__ unsigned short xh[2][MBLK*200];
  __shared__ float relL[MBLK*40];
  __shared__ float pwL[256];          // pred_W[:, :128]
  __shared__ float eW0[64], eW1[64], ebL[64];
  __shared__ float imgcL[MBLK*2];
  __shared__ float biasL[512];        // b_ih + b_hh
  __shared__ float pbL[2];

  const int tid  = threadIdx.x;
  const int wv   = tid >> 6;           // 0..15
  const int lane = tid & 63;
  const int q    = lane >> 4;
  const int i    = lane & 15;
  const int par  = i & 1;              // parity: which mt half this lane owns
  const int j    = wv*8 + (i >> 1);    // hidden unit owned by this lane
  const int g0   = blockIdx.x * MBLK;
  const int dm   = tid >> 5;           // sample 0..31 (32 threads/sample)
  const int i32  = tid & 31;

  // ---- cooperative staging ----
  for (int idx = tid; idx < MBLK*40; idx += 1024) relL[idx] = rel[g0*40 + idx];
  if (tid < 256) pwL[tid] = pW[(tid >> 7)*2176 + (tid & 127)];
  if (tid < 64){ eW0[tid] = eW[tid*2]; eW1[tid] = eW[tid*2+1]; ebL[tid] = eb[tid]; }
  if (tid < 512) biasL[tid] = b_ih[tid] + b_hh[tid];
  if (tid < 2) pbL[tid] = pb[tid];

  // ---- img_embedding @ pred_W[:,128:].T  (once; constant over pred steps) ----
  {
    const float* row = img + (size_t)(g0 + dm)*2048 + i32*64;
    const float* p0  = pW + 128 + i32*64;
    const float* p1  = pW + 2176 + 128 + i32*64;
    float s0 = 0.f, s1 = 0.f;
    #pragma unroll
    for (int v = 0; v < 16; v++){
      float4 a  = ((const float4*)row)[v];
      float4 w0 = ((const float4*)p0)[v];
      float4 w1 = ((const float4*)p1)[v];
      s0 += a.x*w0.x + a.y*w0.y + a.z*w0.z + a.w*w0.w;
      s1 += a.x*w1.x + a.y*w1.y + a.z*w1.z + a.w*w1.w;
    }
    #pragma unroll
    for (int msk = 1; msk < 32; msk <<= 1){
      s0 += __shfl_xor(s0, msk);
      s1 += __shfl_xor(s1, msk);
    }
    if (i32 == 0){ imgcL[dm*2] = s0; imgcL[dm*2+1] = s1; }
  }

  // ---- per-lane persistent state: 4 slots (m = par*16 + q*4 + r, hidden j) ----
  float h0j = h0[j];
  unsigned int thrpk = 0;              // 4 x (20 - hist) packed as bytes
  float c_s[4];
  #pragma unroll
  for (int r = 0; r < 4; r++){
    int m = par*16 + q*4 + r;
    thrpk |= ((unsigned int)((20 - hist[g0 + m]) & 0xFF)) << (8*r);
    c_s[r] = h0j;
    xh[0][m*200 + 64 + j] = f2bf(h0j);
  }

  // ---- weight B-fragments, fp32 -> bf16, register-resident (48 VGPR) ----
  // B-row of tile n2, lane i: (n2*2 + par)*128 + j
  bf16x8 Bf[2][6];
  #pragma unroll
  for (int n2 = 0; n2 < 2; n2++){
    int row = (n2*2 + par)*128 + j;
    #pragma unroll
    for (int kt = 0; kt < 6; kt++){
      const float* src = (kt < 2) ? (W_ih + row*64  + kt*32      + q*8)
                                  : (W_hh + row*128 + (kt-2)*32  + q*8);
      float4 lo = ((const float4*)src)[0];
      float4 hi = ((const float4*)src)[1];
      bf16x8 tf;
      tf[0]=(short)f2bf(lo.x); tf[1]=(short)f2bf(lo.y); tf[2]=(short)f2bf(lo.z); tf[3]=(short)f2bf(lo.w);
      tf[4]=(short)f2bf(hi.x); tf[5]=(short)f2bf(hi.y); tf[6]=(short)f2bf(hi.z); tf[7]=(short)f2bf(hi.w);
      Bf[n2][kt] = tf;
    }
  }

  float pos_r = 0.f;
  if (i32 < 2) pos_r = obs_pos[(size_t)(g0 + dm)*40 + 38 + i32];

  __syncthreads();   // staging (relL, eW*, biasL, imgcL) visible

  // ---- x_emb(t=1) into xh[0] : 2 embed outputs per thread ----
  {
    int e0 = i32*2;
    float r0 = relL[dm*40 + 2], r1 = relL[dm*40 + 3];
    float a0 = fmaxf(0.f, r0*eW0[e0]   + r1*eW1[e0]   + ebL[e0]);
    float a1 = fmaxf(0.f, r0*eW0[e0+1] + r1*eW1[e0+1] + ebL[e0+1]);
    *((unsigned int*)&xh[0][dm*200 + e0]) =
        (unsigned int)f2bf(a0) | ((unsigned int)f2bf(a1) << 16);
  }

  int b = 0;

  for (int step = 0; step < 49; step++){
    const bool obs = (step < 19);
    __syncthreads();     // prev step's writes into xh[b] visible

    if (!obs){
      // ---- disp = h @ pwL + imgc + pb ; 32 threads/sample ----
      bf16x4 hv = *((const bf16x4*)&xh[b][dm*200 + 64 + i32*4]);
      float s0 = 0.f, s1 = 0.f;
      #pragma unroll
      for (int u = 0; u < 4; u++){
        float hf = bf2f((unsigned short)hv[u]);
        s0 += hf * pwL[i32*4 + u];
        s1 += hf * pwL[128 + i32*4 + u];
      }
      s0 += __shfl_xor(s0, 1);  s1 += __shfl_xor(s1, 1);
      s0 += __shfl_xor(s0, 2);  s1 += __shfl_xor(s1, 2);
      s0 += __shfl_xor(s0, 4);  s1 += __shfl_xor(s1, 4);
      s0 += __shfl_xor(s0, 8);  s1 += __shfl_xor(s1, 8);
      s0 += __shfl_xor(s0, 16); s1 += __shfl_xor(s1, 16);
      float d0 = s0 + imgcL[dm*2]   + pbL[0];
      float d1 = s1 + imgcL[dm*2+1] + pbL[1];
      if (i32 < 2){
        pos_r += (i32 == 0) ? d0 : d1;
        out[(size_t)(g0 + dm)*60 + (size_t)(step - 19)*2 + i32] = pos_r;
      }
      int e0 = i32*2;
      float a0 = fmaxf(0.f, d0*eW0[e0]   + d1*eW1[e0]   + ebL[e0]);
      float a1 = fmaxf(0.f, d0*eW0[e0+1] + d1*eW1[e0+1] + ebL[e0+1]);
      *((unsigned int*)&xh[b][dm*200 + e0]) =
          (unsigned int)f2bf(a0) | ((unsigned int)f2bf(a1) << 16);
      __syncthreads();   // x_emb visible before MFMA reads
    }

    // ---- gates = [x|h] @ [W_ih|W_hh].T + b  via MFMA 16x16x32 bf16 ----
    f32x4 acc[2][2];     // [mt][n2]
    #pragma unroll
    for (int n2 = 0; n2 < 2; n2++){
      float bv = biasL[(n2*2 + par)*128 + j];
      acc[0][n2] = (f32x4){bv, bv, bv, bv};
      acc[1][n2] = (f32x4){bv, bv, bv, bv};
    }
    #pragma unroll
    for (int mt = 0; mt < 2; mt++){
      bf16x8 A[6];
      int mrow = mt*16 + i;
      #pragma unroll
      for (int kt = 0; kt < 6; kt++)
        A[kt] = *((const bf16x8*)&xh[b][mrow*200 + kt*32 + q*8]);
      #pragma unroll
      for (int kt = 0; kt < 6; kt++)
        #pragma unroll
        for (int n2 = 0; n2 < 2; n2++)
          acc[mt][n2] = __builtin_amdgcn_mfma_f32_16x16x32_bf16(A[kt], Bf[n2][kt], acc[mt][n2], 0, 0, 0);
    }

    // ---- obs: next step's x_emb (depends only on relL) -> xh[b^1] ----
    if (obs && step < 18){
      int tt = step + 2;               // t+1
      int e0 = i32*2;
      float r0 = relL[dm*40 + tt*2], r1 = relL[dm*40 + tt*2 + 1];
      float a0 = fmaxf(0.f, r0*eW0[e0]   + r1*eW1[e0]   + ebL[e0]);
      float a1 = fmaxf(0.f, r0*eW0[e0+1] + r1*eW1[e0+1] + ebL[e0+1]);
      *((unsigned int*)&xh[b^1][dm*200 + e0]) =
          (unsigned int)f2bf(a0) | ((unsigned int)f2bf(a1) << 16);
    }

    // ---- gate exchange (lanes i <-> i^1) + nonlinearity + state update ----
    // Lane sends acc[par^1] (what partner needs), keeps acc[par].
    #pragma unroll
    for (int r = 0; r < 4; r++){
      float y0 = __shfl_xor(acc[par ^ 1][0][r], 1);
      float y1 = __shfl_xor(acc[par ^ 1][1][r], 1);
      float a0 = acc[par][0][r];
      float a1 = acc[par][1][r];
      float ig = par ? y0 : a0;
      float fg = par ? a0 : y0;
      float gg = par ? y1 : a1;
      float og = par ? a1 : y1;
      float c2 = sigm(fg)*c_s[r] + sigm(ig)*tanh_(gg);
      float h2 = sigm(og)*tanh_(c2);
      unsigned short h2b = f2bf(h2);
      int m = par*16 + q*4 + r;
      if (obs){
        int thr = (int)((thrpk >> (8*r)) & 0xFFu);
        if (step < thr){                       // masked: keep old state
          c2  = c_s[r];
          h2b = xh[b][m*200 + 64 + j];         // old h(t) as bf16, bit-exact
        }
      }
      c_s[r] = c2;
      xh[b^1][m*200 + 64 + j] = h2b;
    }

    b ^= 1;
  }
}

extern "C" void kernel_launch(void* const* d_in, const int* in_sizes, int n_in,
                              void* d_out, int out_size, void* d_ws, size_t ws_size,
                              hipStream_t stream){
  const float* img     = (const float*)d_in[0];
  const float* obs_pos = (const float*)d_in[1];
  const int*   hist    = (const int*)d_in[2];
  const float* rel     = (const float*)d_in[3];
  const float* h0      = (const float*)d_in[4];
  const float* W_ih    = (const float*)d_in[5];
  const float* W_hh    = (const float*)d_in[6];
  const float* b_ih    = (const float*)d_in[7];
  const float* b_hh    = (const float*)d_in[8];
  const float* eW      = (const float*)d_in[9];
  const float* eb      = (const float*)d_in[10];
  const float* pW      = (const float*)d_in[11];
  const float* pb      = (const float*)d_in[12];
  float* out = (float*)d_out;
  hipLaunchKernelGGL(traj_kernel, dim3(8192/MBLK), dim3(1024), 0, stream,
                     img, obs_pos, hist, rel, h0, W_ih, W_hh, b_ih, b_hh,
                     eW, eb, pW, pb, out);
}

// Round 3
// 304.863 us; speedup vs baseline: 1.6065x; 1.6065x over previous
//
#include <hip/hip_runtime.h>

#define MBLK 32

typedef __attribute__((ext_vector_type(8))) short bf16x8;
typedef __attribute__((ext_vector_type(4))) short bf16x4;
typedef __attribute__((ext_vector_type(4))) float f32x4;

__device__ __forceinline__ unsigned short f2bf(float x){
  unsigned int u = __float_as_uint(x);
  u = u + 0x7FFFu + ((u >> 16) & 1u);
  return (unsigned short)(u >> 16);
}
__device__ __forceinline__ float bf2f(unsigned short s){
  return __uint_as_float(((unsigned int)s) << 16);
}
__device__ __forceinline__ float sigm(float x){
  return __builtin_amdgcn_rcpf(1.0f + __expf(-x));
}
__device__ __forceinline__ float tanh_(float x){
  return 1.0f - 2.0f*__builtin_amdgcn_rcpf(__expf(2.0f*x) + 1.0f);
}

// 1024-thread block, 16 waves, MBLK=32, 256 blocks = 1 block/CU,
// __launch_bounds__(1024,4) -> <=128 VGPR -> 4 waves/SIMD.
// Weight B-frags Bf[2][6] = 48 VGPR/thread (196KB weights over 1024 thr).
// Gate split: tile n2, lane i -> gate n2*2+(i&1), hidden wv*8+(i>>1).
// Lane pairs i/i^1 exchange complementary gates via 8 shfl_xor(.,1)/step.
// vs round 2: accumulators are NAMED (a00..a11) and par-selection is done
// with vector ternaries (v_cndmask), never runtime array indexing -> no
// scratch/localMem on the recurrence path (rule #20 fix).
// Double-buffered [x(64)|h(128)] bf16 tile, row stride 200 shorts.
__global__ __launch_bounds__(1024, 4) void traj_kernel(
    const float* __restrict__ img, const float* __restrict__ obs_pos,
    const int* __restrict__ hist, const float* __restrict__ rel,
    const float* __restrict__ h0, const float* __restrict__ W_ih,
    const float* __restrict__ W_hh, const float* __restrict__ b_ih,
    const float* __restrict__ b_hh, const float* __restrict__ eW,
    const float* __restrict__ eb, const float* __restrict__ pW,
    const float* __restrict__ pb, float* __restrict__ out)
{
  __shared__ unsigned short xh[2][MBLK*200];
  __shared__ float relL[MBLK*40];
  __shared__ float pwL[256];          // pred_W[:, :128]
  __shared__ float eW0[64], eW1[64], ebL[64];
  __shared__ float imgcL[MBLK*2];
  __shared__ float biasL[512];        // b_ih + b_hh
  __shared__ float pbL[2];

  const int tid  = threadIdx.x;
  const int wv   = tid >> 6;           // 0..15
  const int lane = tid & 63;
  const int q    = lane >> 4;
  const int i    = lane & 15;
  const int par  = i & 1;              // parity: which mt half this lane owns
  const int j    = wv*8 + (i >> 1);    // hidden unit owned by this lane
  const int g0   = blockIdx.x * MBLK;
  const int dm   = tid >> 5;           // sample 0..31 (32 threads/sample)
  const int i32  = tid & 31;

  // ---- cooperative staging ----
  for (int idx = tid; idx < MBLK*40; idx += 1024) relL[idx] = rel[g0*40 + idx];
  if (tid < 256) pwL[tid] = pW[(tid >> 7)*2176 + (tid & 127)];
  if (tid < 64){ eW0[tid] = eW[tid*2]; eW1[tid] = eW[tid*2+1]; ebL[tid] = eb[tid]; }
  if (tid < 512) biasL[tid] = b_ih[tid] + b_hh[tid];
  if (tid < 2) pbL[tid] = pb[tid];

  // ---- img_embedding @ pred_W[:,128:].T  (once; constant over pred steps) ----
  {
    const float* row = img + (size_t)(g0 + dm)*2048 + i32*64;
    const float* p0  = pW + 128 + i32*64;
    const float* p1  = pW + 2176 + 128 + i32*64;
    float s0 = 0.f, s1 = 0.f;
    #pragma unroll
    for (int v = 0; v < 16; v++){
      float4 a  = ((const float4*)row)[v];
      float4 w0 = ((const float4*)p0)[v];
      float4 w1 = ((const float4*)p1)[v];
      s0 += a.x*w0.x + a.y*w0.y + a.z*w0.z + a.w*w0.w;
      s1 += a.x*w1.x + a.y*w1.y + a.z*w1.z + a.w*w1.w;
    }
    #pragma unroll
    for (int msk = 1; msk < 32; msk <<= 1){
      s0 += __shfl_xor(s0, msk);
      s1 += __shfl_xor(s1, msk);
    }
    if (i32 == 0){ imgcL[dm*2] = s0; imgcL[dm*2+1] = s1; }
  }

  // ---- per-lane persistent state: 4 slots (m = par*16 + q*4 + r, hidden j) ----
  float h0j = h0[j];
  unsigned int thrpk = 0;              // 4 x (20 - hist) packed as bytes
  float c_s[4];
  #pragma unroll
  for (int r = 0; r < 4; r++){
    int m = par*16 + q*4 + r;
    thrpk |= ((unsigned int)((20 - hist[g0 + m]) & 0xFF)) << (8*r);
    c_s[r] = h0j;
    xh[0][m*200 + 64 + j] = f2bf(h0j);
  }

  // ---- weight B-fragments, fp32 -> bf16, register-resident (48 VGPR) ----
  // B-row of tile n2, lane i: (n2*2 + par)*128 + j
  bf16x8 Bf[2][6];
  #pragma unroll
  for (int n2 = 0; n2 < 2; n2++){
    int row = (n2*2 + par)*128 + j;
    #pragma unroll
    for (int kt = 0; kt < 6; kt++){
      const float* src = (kt < 2) ? (W_ih + row*64  + kt*32      + q*8)
                                  : (W_hh + row*128 + (kt-2)*32  + q*8);
      float4 lo = ((const float4*)src)[0];
      float4 hi = ((const float4*)src)[1];
      bf16x8 tf;
      tf[0]=(short)f2bf(lo.x); tf[1]=(short)f2bf(lo.y); tf[2]=(short)f2bf(lo.z); tf[3]=(short)f2bf(lo.w);
      tf[4]=(short)f2bf(hi.x); tf[5]=(short)f2bf(hi.y); tf[6]=(short)f2bf(hi.z); tf[7]=(short)f2bf(hi.w);
      Bf[n2][kt] = tf;
    }
  }

  float pos_r = 0.f;
  if (i32 < 2) pos_r = obs_pos[(size_t)(g0 + dm)*40 + 38 + i32];

  __syncthreads();   // staging (relL, eW*, biasL, imgcL) visible

  // ---- x_emb(t=1) into xh[0] : 2 embed outputs per thread ----
  {
    int e0 = i32*2;
    float r0 = relL[dm*40 + 2], r1 = relL[dm*40 + 3];
    float a0 = fmaxf(0.f, r0*eW0[e0]   + r1*eW1[e0]   + ebL[e0]);
    float a1 = fmaxf(0.f, r0*eW0[e0+1] + r1*eW1[e0+1] + ebL[e0+1]);
    *((unsigned int*)&xh[0][dm*200 + e0]) =
        (unsigned int)f2bf(a0) | ((unsigned int)f2bf(a1) << 16);
  }

  int b = 0;

  for (int step = 0; step < 49; step++){
    const bool obs = (step < 19);
    __syncthreads();     // prev step's writes into xh[b] visible

    if (!obs){
      // ---- disp = h @ pwL + imgc + pb ; 32 threads/sample ----
      bf16x4 hv = *((const bf16x4*)&xh[b][dm*200 + 64 + i32*4]);
      float s0 = 0.f, s1 = 0.f;
      #pragma unroll
      for (int u = 0; u < 4; u++){
        float hf = bf2f((unsigned short)hv[u]);
        s0 += hf * pwL[i32*4 + u];
        s1 += hf * pwL[128 + i32*4 + u];
      }
      s0 += __shfl_xor(s0, 1);  s1 += __shfl_xor(s1, 1);
      s0 += __shfl_xor(s0, 2);  s1 += __shfl_xor(s1, 2);
      s0 += __shfl_xor(s0, 4);  s1 += __shfl_xor(s1, 4);
      s0 += __shfl_xor(s0, 8);  s1 += __shfl_xor(s1, 8);
      s0 += __shfl_xor(s0, 16); s1 += __shfl_xor(s1, 16);
      float d0 = s0 + imgcL[dm*2]   + pbL[0];
      float d1 = s1 + imgcL[dm*2+1] + pbL[1];
      if (i32 < 2){
        pos_r += (i32 == 0) ? d0 : d1;
        out[(size_t)(g0 + dm)*60 + (size_t)(step - 19)*2 + i32] = pos_r;
      }
      int e0 = i32*2;
      float a0 = fmaxf(0.f, d0*eW0[e0]   + d1*eW1[e0]   + ebL[e0]);
      float a1 = fmaxf(0.f, d0*eW0[e0+1] + d1*eW1[e0+1] + ebL[e0+1]);
      *((unsigned int*)&xh[b][dm*200 + e0]) =
          (unsigned int)f2bf(a0) | ((unsigned int)f2bf(a1) << 16);
      __syncthreads();   // x_emb visible before MFMA reads
    }

    // ---- gates = [x|h] @ [W_ih|W_hh].T + b  via MFMA 16x16x32 bf16 ----
    // Named accumulators aMN: M = mt (sample half), N = n2 (gate pair tile).
    const float bv0 = biasL[(par    )*128 + j];   // n2=0 -> gate par
    const float bv1 = biasL[(2 + par)*128 + j];   // n2=1 -> gate 2+par
    f32x4 a00 = (f32x4){bv0, bv0, bv0, bv0};
    f32x4 a01 = (f32x4){bv1, bv1, bv1, bv1};
    f32x4 a10 = a00;
    f32x4 a11 = a01;
    {
      // mt = 0
      bf16x8 A[6];
      #pragma unroll
      for (int kt = 0; kt < 6; kt++)
        A[kt] = *((const bf16x8*)&xh[b][i*200 + kt*32 + q*8]);
      #pragma unroll
      for (int kt = 0; kt < 6; kt++){
        a00 = __builtin_amdgcn_mfma_f32_16x16x32_bf16(A[kt], Bf[0][kt], a00, 0, 0, 0);
        a01 = __builtin_amdgcn_mfma_f32_16x16x32_bf16(A[kt], Bf[1][kt], a01, 0, 0, 0);
      }
    }
    {
      // mt = 1
      bf16x8 A[6];
      #pragma unroll
      for (int kt = 0; kt < 6; kt++)
        A[kt] = *((const bf16x8*)&xh[b][(16 + i)*200 + kt*32 + q*8]);
      #pragma unroll
      for (int kt = 0; kt < 6; kt++){
        a10 = __builtin_amdgcn_mfma_f32_16x16x32_bf16(A[kt], Bf[0][kt], a10, 0, 0, 0);
        a11 = __builtin_amdgcn_mfma_f32_16x16x32_bf16(A[kt], Bf[1][kt], a11, 0, 0, 0);
      }
    }

    // ---- obs: next step's x_emb (depends only on relL) -> xh[b^1] ----
    if (obs && step < 18){
      int tt = step + 2;               // t+1
      int e0 = i32*2;
      float r0 = relL[dm*40 + tt*2], r1 = relL[dm*40 + tt*2 + 1];
      float a0 = fmaxf(0.f, r0*eW0[e0]   + r1*eW1[e0]   + ebL[e0]);
      float a1 = fmaxf(0.f, r0*eW0[e0+1] + r1*eW1[e0+1] + ebL[e0+1]);
      *((unsigned int*)&xh[b^1][dm*200 + e0]) =
          (unsigned int)f2bf(a0) | ((unsigned int)f2bf(a1) << 16);
    }

    // ---- par-selection via vector ternaries (static indexing only) ----
    // self = acc[par][.], send = acc[par^1][.]  (what the partner lane needs)
    f32x4 self0 = par ? a10 : a00;
    f32x4 self1 = par ? a11 : a01;
    f32x4 send0 = par ? a00 : a10;
    f32x4 send1 = par ? a01 : a11;

    // ---- gate exchange (lanes i <-> i^1) + nonlinearity + state update ----
    #pragma unroll
    for (int r = 0; r < 4; r++){
      float y0 = __shfl_xor(send0[r], 1);
      float y1 = __shfl_xor(send1[r], 1);
      float a0 = self0[r];
      float a1 = self1[r];
      float ig = par ? y0 : a0;
      float fg = par ? a0 : y0;
      float gg = par ? y1 : a1;
      float og = par ? a1 : y1;
      float c2 = sigm(fg)*c_s[r] + sigm(ig)*tanh_(gg);
      float h2 = sigm(og)*tanh_(c2);
      unsigned short h2b = f2bf(h2);
      int m = par*16 + q*4 + r;
      if (obs){
        int thr = (int)((thrpk >> (8*r)) & 0xFFu);
        if (step < thr){                       // masked: keep old state
          c2  = c_s[r];
          h2b = xh[b][m*200 + 64 + j];         // old h(t) as bf16, bit-exact
        }
      }
      c_s[r] = c2;
      xh[b^1][m*200 + 64 + j] = h2b;
    }

    b ^= 1;
  }
}

extern "C" void kernel_launch(void* const* d_in, const int* in_sizes, int n_in,
                              void* d_out, int out_size, void* d_ws, size_t ws_size,
                              hipStream_t stream){
  const float* img     = (const float*)d_in[0];
  const float* obs_pos = (const float*)d_in[1];
  const int*   hist    = (const int*)d_in[2];
  const float* rel     = (const float*)d_in[3];
  const float* h0      = (const float*)d_in[4];
  const float* W_ih    = (const float*)d_in[5];
  const float* W_hh    = (const float*)d_in[6];
  const float* b_ih    = (const float*)d_in[7];
  const float* b_hh    = (const float*)d_in[8];
  const float* eW      = (const float*)d_in[9];
  const float* eb      = (const float*)d_in[10];
  const float* pW      = (const float*)d_in[11];
  const float* pb      = (const float*)d_in[12];
  float* out = (float*)d_out;
  hipLaunchKernelGGL(traj_kernel, dim3(8192/MBLK), dim3(1024), 0, stream,
                     img, obs_pos, hist, rel, h0, W_ih, W_hh, b_ih, b_hh,
                     eW, eb, pW, pb, out);
}